// Round 15
// baseline (103.541 us; speedup 1.0000x reference)
//
#include <hip/hip_runtime.h>
#include <hip/hip_bf16.h>

#define B_ 2
#define S_ 2048
#define D_ 768
#define H_ 12
#define BS_ (B_*S_)      // 4096
#define NEGL2 -1.44e12f              // NEG * log2(e)
#define SCALE2 0.18033688f           // (1/sqrt(64)) * log2(e), folded into Q projection

typedef __bf16 bf16;
typedef __attribute__((ext_vector_type(8))) __bf16 bf16x8;
typedef __attribute__((ext_vector_type(4))) float f32x4;
typedef __attribute__((ext_vector_type(16))) float f32x16;

// ---------------- cast fp32 -> bf16 ----------------
__global__ __launch_bounds__(256) void cast_f32_bf16(const float* __restrict__ in,
                                                     bf16* __restrict__ out, int n) {
    int i = (blockIdx.x * 256 + threadIdx.x) * 8;
    if (i + 8 <= n) {
        float4 a = *(const float4*)(in + i);
        float4 b = *(const float4*)(in + i + 4);
        bf16x8 v;
        v[0] = (bf16)a.x; v[1] = (bf16)a.y; v[2] = (bf16)a.z; v[3] = (bf16)a.w;
        v[4] = (bf16)b.x; v[5] = (bf16)b.y; v[6] = (bf16)b.z; v[7] = (bf16)b.w;
        *(bf16x8*)(out + i) = v;
    }
}

// ---------------- 4x W (K x N, fp32) -> Wt (N x K, bf16), batched ----------------
__global__ __launch_bounds__(256) void transpose_w4(const float* __restrict__ W0,
                                                    const float* __restrict__ W1,
                                                    const float* __restrict__ W2,
                                                    const float* __restrict__ W3,
                                                    bf16* __restrict__ Wt0) {
    const float* Ws[4] = {W0, W1, W2, W3};
    const float* W = Ws[blockIdx.z];
    bf16* Wt = Wt0 + (size_t)blockIdx.z * D_ * D_;   // Wqt|Wkt|Wvt|Wot contiguous
    __shared__ float tile[16][17];
    int bx = blockIdx.x, by = blockIdx.y;
    int tx = threadIdx.x & 15, ty = threadIdx.x >> 4;
    tile[ty][tx] = W[(by * 16 + ty) * D_ + bx * 16 + tx];
    __syncthreads();
    Wt[(bx * 16 + ty) * D_ + by * 16 + tx] = (bf16)tile[tx][ty];
}

// ---------------- helpers ----------------
__device__ inline unsigned pk2(float a, float b) {
    union { unsigned u; __bf16 h[2]; } x;
    x.h[0] = (__bf16)a; x.h[1] = (__bf16)b;
    return x.u;
}

// ---------------- fused QKV GEMM: 64x128 tile, BK=64, REG-STAGED T14, swizzled LDS ----------------
// Bt = [2304][768] bf16 (Wq^T|Wk^T|Wv^T). grid (64, 18). mid = bn/6.
// v10-style schedule: barrier -> ds_write(staged regs) -> barrier -> LOAD(kt+1) -> compute(kt).
// Global-load latency for tile kt+1 hides under compute(kt) + both barriers.
// LDS stays 24KB single-buffered (4.5 blocks/CU preserved).
// LDS image: LDS[row][chunk16B] = G[row][chunk ^ (row&7)]; reads XOR the same.
__global__ __launch_bounds__(256) void gemm_qkv(const bf16* __restrict__ A,
                                                const bf16* __restrict__ Bt,
                                                const float* __restrict__ bq,
                                                const float* __restrict__ bk,
                                                const float* __restrict__ bv,
                                                bf16* __restrict__ Qo,
                                                bf16* __restrict__ Ko,
                                                bf16* __restrict__ Vo) {
    constexpr int K = 768;
    __shared__ __align__(16) bf16 As[64 * 64];    // 8KB  (rows of 128B)
    __shared__ __align__(16) bf16 Bs[128 * 64];   // 16KB
    const int bm = blockIdx.x, bn = blockIdx.y;
    const int t = threadIdx.x;
    const int lane = t & 63, wid = t >> 6;
    const int wm = wid >> 1, wn = wid & 1;
    f32x4 acc[2][4] = {};

    const char* gA = (const char*)(A + (size_t)(bm * 64) * K);
    const char* gB = (const char*)(Bt + (size_t)(bn * 128) * K);
    const int srow = wid * 8 + (lane >> 3);           // +32 per chunk
    const int chg = ((lane & 7) ^ (lane >> 3)) * 16;  // pre-swizzled global chunk
    char* dA = (char*)As + wid * 1024 + lane * 16;    // +4096 per chunk (c*32 rows)
    char* dB = (char*)Bs + wid * 1024 + lane * 16;

    bf16x8 sA[2], sB[4];
    auto LOADG = [&](int kt) {
#pragma unroll
        for (int c = 0; c < 2; ++c)
            sA[c] = *(const bf16x8*)(gA + (size_t)(c * 32 + srow) * (K * 2) + kt * 128 + chg);
#pragma unroll
        for (int c = 0; c < 4; ++c)
            sB[c] = *(const bf16x8*)(gB + (size_t)(c * 32 + srow) * (K * 2) + kt * 128 + chg);
    };

    LOADG(0);

    for (int kt = 0; kt < 12; ++kt) {
        __syncthreads();   // readers of previous tile done; LDS free
#pragma unroll
        for (int c = 0; c < 2; ++c) *(bf16x8*)(dA + c * 4096) = sA[c];
#pragma unroll
        for (int c = 0; c < 4; ++c) *(bf16x8*)(dB + c * 4096) = sB[c];
        __syncthreads();   // tile visible
        if (kt < 11) LOADG(kt + 1);   // T14: issue next tile's loads before compute

#pragma unroll
        for (int kb = 0; kb < 2; ++kb) {
            const int chunk = ((kb * 4 + (lane >> 4)) ^ (lane & 7)) * 16;
            bf16x8 aF[2], bF[4];
#pragma unroll
            for (int mf = 0; mf < 2; ++mf)
                aF[mf] = *(const bf16x8*)((const char*)As + (wm * 32 + mf * 16 + (lane & 15)) * 128 + chunk);
#pragma unroll
            for (int nf = 0; nf < 4; ++nf)
                bF[nf] = *(const bf16x8*)((const char*)Bs + (wn * 64 + nf * 16 + (lane & 15)) * 128 + chunk);
#pragma unroll
            for (int mf = 0; mf < 2; ++mf)
#pragma unroll
                for (int nf = 0; nf < 4; ++nf)
                    acc[mf][nf] = __builtin_amdgcn_mfma_f32_16x16x32_bf16(aF[mf], bF[nf], acc[mf][nf], 0, 0, 0);
        }
    }

    const int mid = bn / 6;
    const float* bias = (mid == 0) ? bq : (mid == 1) ? bk : bv;
#pragma unroll
    for (int mf = 0; mf < 2; ++mf) {
#pragma unroll
        for (int nf = 0; nf < 4; ++nf) {
#pragma unroll
            for (int r = 0; r < 4; ++r) {
                int row = bm * 64 + wm * 32 + mf * 16 + (lane >> 4) * 4 + r;
                int lc = (bn - mid * 6) * 128 + wn * 64 + nf * 16 + (lane & 15);
                float v = acc[mf][nf][r] + bias[lc];
                if (mid == 0) {
                    Qo[(size_t)row * D_ + lc] = (bf16)(v * SCALE2);   // pre-scaled Q
                } else if (mid == 1) {
                    Ko[(size_t)row * D_ + lc] = (bf16)v;
                } else {
                    int bb = row >> 11, s = row & 2047, hh = lc >> 6, nn = lc & 63;
                    Vo[(size_t)(((bb * H_ + hh) << 6) + nn) * S_ + s] = (bf16)v;   // V^T per head
                }
            }
        }
    }
}

// ---------------- output GEMM: 32x128 tile, BK=64, REG-STAGED T14, swizzled; fp32 out ----------------
// grid (128, 6) = 768 blocks = 3/CU exact. Same v10-style schedule as gemm_qkv.
__global__ __launch_bounds__(256) void gemm_out(const bf16* __restrict__ A,
                                                const bf16* __restrict__ Bt,
                                                const float* __restrict__ bias,
                                                float* __restrict__ Cout) {
    constexpr int K = 768;
    __shared__ __align__(16) bf16 As[32 * 64];    // 4KB
    __shared__ __align__(16) bf16 Bs[128 * 64];   // 16KB
    const int bm = blockIdx.x, bn = blockIdx.y;
    const int t = threadIdx.x;
    const int lane = t & 63, wid = t >> 6;
    const int wm = wid >> 1, wn = wid & 1;
    f32x4 acc[4] = {};

    const char* gA = (const char*)(A + (size_t)(bm * 32) * K);
    const char* gB = (const char*)(Bt + (size_t)(bn * 128) * K);
    const int srow = wid * 8 + (lane >> 3);
    const int chg = ((lane & 7) ^ (lane >> 3)) * 16;
    char* dA = (char*)As + wid * 1024 + lane * 16;
    char* dB = (char*)Bs + wid * 1024 + lane * 16;

    bf16x8 sA, sB[4];
    auto LOADG = [&](int kt) {
        sA = *(const bf16x8*)(gA + (size_t)srow * (K * 2) + kt * 128 + chg);
#pragma unroll
        for (int c = 0; c < 4; ++c)
            sB[c] = *(const bf16x8*)(gB + (size_t)(c * 32 + srow) * (K * 2) + kt * 128 + chg);
    };

    LOADG(0);

    for (int kt = 0; kt < 12; ++kt) {
        __syncthreads();
        *(bf16x8*)dA = sA;
#pragma unroll
        for (int c = 0; c < 4; ++c) *(bf16x8*)(dB + c * 4096) = sB[c];
        __syncthreads();
        if (kt < 11) LOADG(kt + 1);

#pragma unroll
        for (int kb = 0; kb < 2; ++kb) {
            const int chunk = ((kb * 4 + (lane >> 4)) ^ (lane & 7)) * 16;
            bf16x8 aF = *(const bf16x8*)((const char*)As + (wm * 16 + (lane & 15)) * 128 + chunk);
            bf16x8 bF[4];
#pragma unroll
            for (int nf = 0; nf < 4; ++nf)
                bF[nf] = *(const bf16x8*)((const char*)Bs + (wn * 64 + nf * 16 + (lane & 15)) * 128 + chunk);
#pragma unroll
            for (int nf = 0; nf < 4; ++nf)
                acc[nf] = __builtin_amdgcn_mfma_f32_16x16x32_bf16(aF, bF[nf], acc[nf], 0, 0, 0);
        }
    }

#pragma unroll
    for (int nf = 0; nf < 4; ++nf)
#pragma unroll
        for (int r = 0; r < 4; ++r) {
            int row = bm * 32 + wm * 16 + (lane >> 4) * 4 + r;
            int col = bn * 128 + wn * 64 + nf * 16 + (lane & 15);
            Cout[(size_t)row * D_ + col] = acc[nf][r] + bias[col];
        }
}

// ---------------- flash attention v10 (best-measured: 46.9 us; unchanged) ----------------
// grid (32 qtiles of 64 rows, 24 b*h) = 768 blocks = 3 blocks/CU EXACT.
// 256 threads = 4 waves. wave w: qs = w&1, half = w>>1 (1024 kv).
// Staging role = w&1 (0: K, 1: V), T14 reg-prefetch, single 32KB LDS buffer,
// 2-way merge epilogue. Max-free softmax with native v_exp_f32.
__global__ __launch_bounds__(256, 3) void attn_fwd10(const bf16* __restrict__ Qs,
                                                     const bf16* __restrict__ Kg,
                                                     const bf16* __restrict__ Vt,
                                                     const int* __restrict__ masks,
                                                     bf16* __restrict__ Oa) {
    __shared__ __align__(16) char Sbuf[2][16384];   // [half][ K 8K | V 8K ], swizzled image
    __shared__ float Lr[2][64];

    const int qt = blockIdx.x, bh = blockIdx.y;
    const int b = bh / H_, h = bh % H_;
    const int t = threadIdx.x;
    const int lane = t & 63, w = t >> 6;
    const int lo = lane & 31, hi = lane >> 5;
    const int half = w >> 1;
    const int qs = w & 1;
    const int role = w & 1;

    // per-half mask flags: nibble per 64-kv tile (any masked col); lane covers 16 kv
    unsigned long long mflags;
    {
        const int* mb = masks + b * S_ + half * 1024 + lane * 16;
        int anyz = 0;
#pragma unroll
        for (int u = 0; u < 4; ++u) {
            int4 mv = *(const int4*)(mb + u * 4);
            anyz |= (!mv.x) | (!mv.y) | (!mv.z) | (!mv.w);
        }
        mflags = __ballot(anyz != 0);
    }

    // hoist Q fragments (B operand of swapped QK), Q pre-scaled by SCALE2
    bf16x8 bQ[4];
    {
        const bf16* qp = Qs + (size_t)(b * S_ + qt * 64 + qs * 32 + lo) * D_ + h * 64 + 8 * hi;
#pragma unroll
        for (int kb = 0; kb < 4; ++kb) bQ[kb] = *(const bf16x8*)(qp + 16 * kb);
    }

    // staging geometry: linear global read, XOR-swizzled LDS write
    const int srow = lane >> 3;
    const int scolS = ((lane & 7) * 16) ^ ((srow & 7) << 4);
    const char* gsrc;
    size_t cstride, tstep;
    if (role == 0) {   // K[b][s][h*64..]: tile rows are s
        gsrc = (const char*)Kg + ((size_t)(b * S_ + half * 1024 + srow) * D_ + h * 64) * 2 + scolS;
        cstride = (size_t)8 * D_ * 2;
        tstep = (size_t)64 * D_ * 2;
    } else {           // V^T[bh][n][s]: tile rows are n, cols advance along s
        gsrc = (const char*)Vt + ((size_t)(bh * 64 + srow) * S_ + half * 1024) * 2 + scolS;
        cstride = (size_t)8 * S_ * 2;
        tstep = 128;
    }
    char* dst = &Sbuf[half][0] + role * 8192 + lane * 16;
    const char* Kh = &Sbuf[half][0];
    const char* Vh = Kh + 8192;

    bf16x8 sreg[8];
#pragma unroll
    for (int j = 0; j < 8; ++j) sreg[j] = *(const bf16x8*)(gsrc + j * cstride);

    f32x16 oo[2] = {};
    float lrun = 0.f;

#pragma unroll 1
    for (int kt = 0; kt < 16; ++kt) {
        __syncthreads();   // prior readers done, LDS free
#pragma unroll
        for (int j = 0; j < 8; ++j) *(bf16x8*)(dst + j * 1024) = sreg[j];
        __syncthreads();   // tile visible to all 4 waves
        if (kt < 15) {     // T14: issue next tile's loads; land during compute
            const char* p = gsrc + (size_t)(kt + 1) * tstep;
#pragma unroll
            for (int j = 0; j < 8; ++j) sreg[j] = *(const bf16x8*)(p + j * cstride);
        }

        const bool mk = (mflags >> (4 * kt)) & 0xFULL;
        float lsum = 0.f;
#pragma unroll
        for (int kb2 = 0; kb2 < 2; ++kb2) {
            const int row = kb2 * 32 + lo;
            const int rsw = (row & 7) << 4;
            f32x16 sa = {};
            __builtin_amdgcn_s_setprio(1);
#pragma unroll
            for (int kb = 0; kb < 4; ++kb) {
                bf16x8 aK = *(const bf16x8*)(Kh + row * 128 + ((kb * 32 + hi * 16) ^ rsw));
                sa = __builtin_amdgcn_mfma_f32_32x32x16_bf16(aK, bQ[kb], sa, 0, 0, 0);
            }
            __builtin_amdgcn_s_setprio(0);
            float pp[16];
            if (!mk) {
#pragma unroll
                for (int r = 0; r < 16; ++r) pp[r] = __builtin_amdgcn_exp2f(sa[r]);
            } else {
#pragma unroll
                for (int r = 0; r < 16; ++r) {
                    int kv = half * 1024 + kt * 64 + kb2 * 32 + (r & 3) + 8 * (r >> 2) + 4 * hi;
                    float madd = masks[b * S_ + kv] ? 0.f : NEGL2;
                    pp[r] = __builtin_amdgcn_exp2f(sa[r] + madd);
                }
            }
            float s8[8];
#pragma unroll
            for (int i = 0; i < 8; ++i) s8[i] = pp[i] + pp[i + 8];
            lsum += ((s8[0] + s8[1]) + (s8[2] + s8[3])) + ((s8[4] + s8[5]) + (s8[6] + s8[7]));

#pragma unroll
            for (int ks2 = 0; ks2 < 2; ++ks2) {
                const float* q8 = pp + ks2 * 8;
                unsigned u0 = pk2(q8[0], q8[1]);
                unsigned u1 = pk2(q8[2], q8[3]);
                unsigned u2 = pk2(q8[4], q8[5]);
                unsigned u3 = pk2(q8[6], q8[7]);
                asm("v_permlane32_swap_b32 %0, %1" : "+v"(u0), "+v"(u2));
                asm("v_permlane32_swap_b32 %0, %1" : "+v"(u1), "+v"(u3));
                union { unsigned u[4]; bf16x8 v; } pa;
                pa.u[0] = u0; pa.u[1] = u1; pa.u[2] = u2; pa.u[3] = u3;
                const int ks = kb2 * 2 + ks2;
                __builtin_amdgcn_s_setprio(1);
#pragma unroll
                for (int nb = 0; nb < 2; ++nb) {
                    const int vr = nb * 32 + lo;
                    bf16x8 aV = *(const bf16x8*)(Vh + vr * 128 +
                                                 ((ks * 32 + hi * 16) ^ ((vr & 7) << 4)));
                    oo[nb] = __builtin_amdgcn_mfma_f32_32x32x16_bf16(aV, pa.v, oo[nb], 0, 0, 0);
                }
                __builtin_amdgcn_s_setprio(0);
            }
        }
        lrun += lsum + __shfl_xor(lsum, 32, 64);
    }

    // ---- merge: waves 2,3 (half 1) hand partials to waves 0,1 (half 0) ----
    __syncthreads();
    float* mbuf = (float*)&Sbuf[0][0];   // 16KB = 2 q-subs x 2048 floats
    if (w >= 2) {
        float* d = mbuf + qs * 2048;
#pragma unroll
        for (int nb = 0; nb < 2; ++nb)
#pragma unroll
            for (int r = 0; r < 16; ++r)
                d[(nb * 16 + r) * 64 + lane] = oo[nb][r];
        Lr[qs][lane] = lrun;
    }
    __syncthreads();
    if (w < 2) {
        const float* s = mbuf + qs * 2048;
#pragma unroll
        for (int nb = 0; nb < 2; ++nb)
#pragma unroll
            for (int r = 0; r < 16; ++r)
                oo[nb][r] += s[(nb * 16 + r) * 64 + lane];
        float inv = 1.f / (lrun + Lr[qs][lane]);

        // transpose O^T -> O via LDS scratch (disjoint from mbuf), coalesced store
        char* ot = (char*)&Sbuf[1][0] + qs * 8192;   // [32 q][72 n] bf16
#pragma unroll
        for (int nb = 0; nb < 2; ++nb)
#pragma unroll
            for (int tq = 0; tq < 4; ++tq) {
                int n0 = tq * 8 + hi * 4 + nb * 32;
                *(unsigned*)(ot + lo * 144 + n0 * 2) =
                    pk2(oo[nb][tq * 4 + 0] * inv, oo[nb][tq * 4 + 1] * inv);
                *(unsigned*)(ot + lo * 144 + n0 * 2 + 4) =
                    pk2(oo[nb][tq * 4 + 2] * inv, oo[nb][tq * 4 + 3] * inv);
            }
#pragma unroll
        for (int pass = 0; pass < 4; ++pass) {
            int chunk = hi + pass * 2;
            bf16x8 vv = *(const bf16x8*)(ot + lo * 144 + chunk * 16);
            *(bf16x8*)(Oa + (size_t)(b * S_ + qt * 64 + qs * 32 + lo) * D_ + h * 64 + chunk * 8) = vv;
        }
    }
}

extern "C" void kernel_launch(void* const* d_in, const int* in_sizes, int n_in,
                              void* d_out, int out_size, void* d_ws, size_t ws_size,
                              hipStream_t stream) {
    (void)in_sizes; (void)n_in; (void)out_size; (void)ws_size;
    const float* x  = (const float*)d_in[0];
    const int* masks = (const int*)d_in[1];
    const float* Wq = (const float*)d_in[2];
    const float* bq = (const float*)d_in[3];
    const float* Wk = (const float*)d_in[4];
    const float* bk = (const float*)d_in[5];
    const float* Wv = (const float*)d_in[6];
    const float* bv = (const float*)d_in[7];
    const float* Wo = (const float*)d_in[8];
    const float* bo = (const float*)d_in[9];
    float* out = (float*)d_out;

    char* ws = (char*)d_ws;
    size_t off = 0;
    auto alloc = [&](size_t bytes) {
        void* p = ws + off;
        off += (bytes + 255) & ~(size_t)255;
        return p;
    };
    bf16* Xb  = (bf16*)alloc((size_t)BS_ * D_ * 2);
    // NOTE: Wqt..Wot must stay contiguous (transpose_w4 / gemm_qkv rely on it)
    bf16* Wqt = (bf16*)alloc((size_t)D_ * D_ * 2);
    bf16* Wkt = (bf16*)alloc((size_t)D_ * D_ * 2);
    bf16* Wvt = (bf16*)alloc((size_t)D_ * D_ * 2);
    bf16* Wot = (bf16*)alloc((size_t)D_ * D_ * 2);
    bf16* Qb  = (bf16*)alloc((size_t)BS_ * D_ * 2);
    bf16* Kb2 = (bf16*)alloc((size_t)BS_ * D_ * 2);
    bf16* Vtb = (bf16*)alloc((size_t)BS_ * D_ * 2);
    bf16* Ab  = (bf16*)alloc((size_t)BS_ * D_ * 2);
    (void)Wkt; (void)Wvt;

    cast_f32_bf16<<<(BS_ * D_) / 2048, 256, 0, stream>>>(x, Xb, BS_ * D_);
    transpose_w4<<<dim3(48, 48, 4), 256, 0, stream>>>(Wq, Wk, Wv, Wo, Wqt);

    gemm_qkv<<<dim3(64, 18), 256, 0, stream>>>(Xb, Wqt, bq, bk, bv, Qb, Kb2, Vtb);

    attn_fwd10<<<dim3(32, 24), 256, 0, stream>>>(Qb, Kb2, Vtb, masks, Ab);

    gemm_out<<<dim3(128, 6), 256, 0, stream>>>(Ab, Wot, bo, out);
}

// Round 16
// 95.423 us; speedup vs baseline: 1.0851x; 1.0851x over previous
//
#include <hip/hip_runtime.h>
#include <hip/hip_bf16.h>

#define B_ 2
#define S_ 2048
#define D_ 768
#define H_ 12
#define BS_ (B_*S_)      // 4096
#define NEGL2 -1.44e12f              // NEG * log2(e)
#define SCALE2 0.18033688f           // (1/sqrt(64)) * log2(e), folded into Q projection

typedef __bf16 bf16;
typedef __attribute__((ext_vector_type(8))) __bf16 bf16x8;
typedef __attribute__((ext_vector_type(4))) float f32x4;
typedef __attribute__((ext_vector_type(16))) float f32x16;

// ---------------- helpers ----------------
__device__ inline unsigned pk2(float a, float b) {
    union { unsigned u; __bf16 h[2]; } x;
    x.h[0] = (__bf16)a; x.h[1] = (__bf16)b;
    return x.u;
}

__device__ __forceinline__ void gload16(const void* g, void* l) {
    __builtin_amdgcn_global_load_lds(
        (const __attribute__((address_space(1))) unsigned int*)g,
        (__attribute__((address_space(3))) unsigned int*)l, 16, 0, 0);
}

// ---------------- fused prep: cast X -> bf16 AND transpose 4x W -> bf16 ----------------
// blocks [0,1536): cast (8 floats/thread, exact coverage of 4096*768).
// blocks [1536, 1536+576): W transpose in 64x64 tiles (float4 loads, LDS [64][68]
// keeps float4 rows 16B-aligned; column read 4-way conflict; coalesced bf16 row writes).
__global__ __launch_bounds__(256) void prep(const float* __restrict__ x,
                                            const float* __restrict__ Wq,
                                            const float* __restrict__ Wk,
                                            const float* __restrict__ Wv,
                                            const float* __restrict__ Wo,
                                            bf16* __restrict__ Xb,
                                            bf16* __restrict__ Wt0) {
    int id = blockIdx.x;
    if (id < 1536) {
        int i = (id * 256 + threadIdx.x) * 8;
        float4 a = *(const float4*)(x + i);
        float4 b = *(const float4*)(x + i + 4);
        bf16x8 v;
        v[0] = (bf16)a.x; v[1] = (bf16)a.y; v[2] = (bf16)a.z; v[3] = (bf16)a.w;
        v[4] = (bf16)b.x; v[5] = (bf16)b.y; v[6] = (bf16)b.z; v[7] = (bf16)b.w;
        *(bf16x8*)(Xb + i) = v;
        return;
    }
    id -= 1536;
    const int z = id / 144;          // which matrix
    const int rem = id % 144;
    const int by = rem / 12;         // row-tile of W (k dim)
    const int bx = rem % 12;         // col-tile of W (n dim)
    const float* W = (z == 0) ? Wq : (z == 1) ? Wk : (z == 2) ? Wv : Wo;
    bf16* Wt = Wt0 + (size_t)z * D_ * D_;   // Wqt|Wkt|Wvt|Wot contiguous

    __shared__ float tile[64][68];   // 68-stride: float4 rows stay 16B-aligned
    const int r = threadIdx.x >> 2;          // 0..63
    const int c = (threadIdx.x & 3) * 16;    // 0,16,32,48

    const float* src = W + (size_t)(by * 64 + r) * D_ + bx * 64 + c;
    *(float4*)&tile[r][c + 0]  = *(const float4*)(src + 0);
    *(float4*)&tile[r][c + 4]  = *(const float4*)(src + 4);
    *(float4*)&tile[r][c + 8]  = *(const float4*)(src + 8);
    *(float4*)&tile[r][c + 12] = *(const float4*)(src + 12);
    __syncthreads();

    // Wt[n][k] = W[k][n]: output row n = bx*64 + r, cols k = by*64 + c .. c+15
    bf16 ov[16];
#pragma unroll
    for (int j = 0; j < 16; ++j) ov[j] = (bf16)tile[c + j][r];
    bf16* dst = Wt + (size_t)(bx * 64 + r) * D_ + by * 64 + c;
    *(bf16x8*)dst = *(bf16x8*)&ov[0];
    *(bf16x8*)(dst + 8) = *(bf16x8*)&ov[8];
}

// ---------------- fused QKV GEMM: 64x128 tile, BK=64, gload_lds, swizzled LDS ----------------
// (round-14 best config: single-buffered, grid (64,18), 24KB LDS, 4.5 blocks/CU)
__global__ __launch_bounds__(256) void gemm_qkv(const bf16* __restrict__ A,
                                                const bf16* __restrict__ Bt,
                                                const float* __restrict__ bq,
                                                const float* __restrict__ bk,
                                                const float* __restrict__ bv,
                                                bf16* __restrict__ Qo,
                                                bf16* __restrict__ Ko,
                                                bf16* __restrict__ Vo) {
    constexpr int K = 768;
    __shared__ __align__(16) bf16 As[64 * 64];    // 8KB  (rows of 128B)
    __shared__ __align__(16) bf16 Bs[128 * 64];   // 16KB
    const int bm = blockIdx.x, bn = blockIdx.y;
    const int t = threadIdx.x;
    const int lane = t & 63, wid = t >> 6;
    const int wm = wid >> 1, wn = wid & 1;
    f32x4 acc[2][4] = {};

    const char* gA = (const char*)(A + (size_t)(bm * 64) * K);
    const char* gB = (const char*)(Bt + (size_t)(bn * 128) * K);
    const int srow = wid * 8 + (lane >> 3);           // +32 per call
    const int chg = ((lane & 7) ^ (lane >> 3)) * 16;  // pre-swizzled global chunk

    for (int kt = 0; kt < 12; ++kt) {
        __syncthreads();   // readers of previous tile done
#pragma unroll
        for (int c = 0; c < 2; ++c)
            gload16(gA + (size_t)(c * 32 + srow) * (K * 2) + kt * 128 + chg,
                    (char*)As + c * 4096 + wid * 1024);
#pragma unroll
        for (int c = 0; c < 4; ++c)
            gload16(gB + (size_t)(c * 32 + srow) * (K * 2) + kt * 128 + chg,
                    (char*)Bs + c * 4096 + wid * 1024);
        asm volatile("s_waitcnt vmcnt(0)");
        __syncthreads();   // tile ready

#pragma unroll
        for (int kb = 0; kb < 2; ++kb) {
            const int chunk = ((kb * 4 + (lane >> 4)) ^ (lane & 7)) * 16;
            bf16x8 aF[2], bF[4];
#pragma unroll
            for (int mf = 0; mf < 2; ++mf)
                aF[mf] = *(const bf16x8*)((const char*)As + (wm * 32 + mf * 16 + (lane & 15)) * 128 + chunk);
#pragma unroll
            for (int nf = 0; nf < 4; ++nf)
                bF[nf] = *(const bf16x8*)((const char*)Bs + (wn * 64 + nf * 16 + (lane & 15)) * 128 + chunk);
#pragma unroll
            for (int mf = 0; mf < 2; ++mf)
#pragma unroll
                for (int nf = 0; nf < 4; ++nf)
                    acc[mf][nf] = __builtin_amdgcn_mfma_f32_16x16x32_bf16(aF[mf], bF[nf], acc[mf][nf], 0, 0, 0);
        }
    }

    const int mid = bn / 6;
    const float* bias = (mid == 0) ? bq : (mid == 1) ? bk : bv;
#pragma unroll
    for (int mf = 0; mf < 2; ++mf) {
#pragma unroll
        for (int nf = 0; nf < 4; ++nf) {
#pragma unroll
            for (int r = 0; r < 4; ++r) {
                int row = bm * 64 + wm * 32 + mf * 16 + (lane >> 4) * 4 + r;
                int lc = (bn - mid * 6) * 128 + wn * 64 + nf * 16 + (lane & 15);
                float v = acc[mf][nf][r] + bias[lc];
                if (mid == 0) {
                    Qo[(size_t)row * D_ + lc] = (bf16)(v * SCALE2);   // pre-scaled Q
                } else if (mid == 1) {
                    Ko[(size_t)row * D_ + lc] = (bf16)v;
                } else {
                    int bb = row >> 11, s = row & 2047, hh = lc >> 6, nn = lc & 63;
                    Vo[(size_t)(((bb * H_ + hh) << 6) + nn) * S_ + s] = (bf16)v;   // V^T per head
                }
            }
        }
    }
}

// ---------------- output GEMM: 32x128 tile, BK=64, gload_lds, swizzled; fp32 out ----------------
// (round-14 best config: single-buffered, grid (128,6) = 3 blocks/CU exact)
__global__ __launch_bounds__(256) void gemm_out(const bf16* __restrict__ A,
                                                const bf16* __restrict__ Bt,
                                                const float* __restrict__ bias,
                                                float* __restrict__ Cout) {
    constexpr int K = 768;
    __shared__ __align__(16) bf16 As[32 * 64];    // 4KB
    __shared__ __align__(16) bf16 Bs[128 * 64];   // 16KB
    const int bm = blockIdx.x, bn = blockIdx.y;
    const int t = threadIdx.x;
    const int lane = t & 63, wid = t >> 6;
    const int wm = wid >> 1, wn = wid & 1;
    f32x4 acc[4] = {};

    const char* gA = (const char*)(A + (size_t)(bm * 32) * K);
    const char* gB = (const char*)(Bt + (size_t)(bn * 128) * K);
    const int srow = wid * 8 + (lane >> 3);
    const int chg = ((lane & 7) ^ (lane >> 3)) * 16;

    for (int kt = 0; kt < 12; ++kt) {
        __syncthreads();
        gload16(gA + (size_t)srow * (K * 2) + kt * 128 + chg,
                (char*)As + wid * 1024);
#pragma unroll
        for (int c = 0; c < 4; ++c)
            gload16(gB + (size_t)(c * 32 + srow) * (K * 2) + kt * 128 + chg,
                    (char*)Bs + c * 4096 + wid * 1024);
        asm volatile("s_waitcnt vmcnt(0)");
        __syncthreads();

#pragma unroll
        for (int kb = 0; kb < 2; ++kb) {
            const int chunk = ((kb * 4 + (lane >> 4)) ^ (lane & 7)) * 16;
            bf16x8 aF = *(const bf16x8*)((const char*)As + (wm * 16 + (lane & 15)) * 128 + chunk);
            bf16x8 bF[4];
#pragma unroll
            for (int nf = 0; nf < 4; ++nf)
                bF[nf] = *(const bf16x8*)((const char*)Bs + (wn * 64 + nf * 16 + (lane & 15)) * 128 + chunk);
#pragma unroll
            for (int nf = 0; nf < 4; ++nf)
                acc[nf] = __builtin_amdgcn_mfma_f32_16x16x32_bf16(aF, bF[nf], acc[nf], 0, 0, 0);
        }
    }

#pragma unroll
    for (int nf = 0; nf < 4; ++nf)
#pragma unroll
        for (int r = 0; r < 4; ++r) {
            int row = bm * 32 + wm * 16 + (lane >> 4) * 4 + r;
            int col = bn * 128 + wn * 64 + nf * 16 + (lane & 15);
            Cout[(size_t)row * D_ + col] = acc[nf][r] + bias[col];
        }
}

// ---------------- flash attention v10 (best-measured: 46.9 us; unchanged) ----------------
// grid (32 qtiles of 64 rows, 24 b*h) = 768 blocks = 3 blocks/CU EXACT.
// 256 threads = 4 waves. wave w: qs = w&1, half = w>>1 (1024 kv).
// Staging role = w&1 (0: K, 1: V), T14 reg-prefetch, single 32KB LDS buffer,
// 2-way merge epilogue. Max-free softmax with native v_exp_f32.
__global__ __launch_bounds__(256, 3) void attn_fwd10(const bf16* __restrict__ Qs,
                                                     const bf16* __restrict__ Kg,
                                                     const bf16* __restrict__ Vt,
                                                     const int* __restrict__ masks,
                                                     bf16* __restrict__ Oa) {
    __shared__ __align__(16) char Sbuf[2][16384];   // [half][ K 8K | V 8K ], swizzled image
    __shared__ float Lr[2][64];

    const int qt = blockIdx.x, bh = blockIdx.y;
    const int b = bh / H_, h = bh % H_;
    const int t = threadIdx.x;
    const int lane = t & 63, w = t >> 6;
    const int lo = lane & 31, hi = lane >> 5;
    const int half = w >> 1;
    const int qs = w & 1;
    const int role = w & 1;

    // per-half mask flags: nibble per 64-kv tile (any masked col); lane covers 16 kv
    unsigned long long mflags;
    {
        const int* mb = masks + b * S_ + half * 1024 + lane * 16;
        int anyz = 0;
#pragma unroll
        for (int u = 0; u < 4; ++u) {
            int4 mv = *(const int4*)(mb + u * 4);
            anyz |= (!mv.x) | (!mv.y) | (!mv.z) | (!mv.w);
        }
        mflags = __ballot(anyz != 0);
    }

    // hoist Q fragments (B operand of swapped QK), Q pre-scaled by SCALE2
    bf16x8 bQ[4];
    {
        const bf16* qp = Qs + (size_t)(b * S_ + qt * 64 + qs * 32 + lo) * D_ + h * 64 + 8 * hi;
#pragma unroll
        for (int kb = 0; kb < 4; ++kb) bQ[kb] = *(const bf16x8*)(qp + 16 * kb);
    }

    // staging geometry: linear global read, XOR-swizzled LDS write
    const int srow = lane >> 3;
    const int scolS = ((lane & 7) * 16) ^ ((srow & 7) << 4);
    const char* gsrc;
    size_t cstride, tstep;
    if (role == 0) {   // K[b][s][h*64..]: tile rows are s
        gsrc = (const char*)Kg + ((size_t)(b * S_ + half * 1024 + srow) * D_ + h * 64) * 2 + scolS;
        cstride = (size_t)8 * D_ * 2;
        tstep = (size_t)64 * D_ * 2;
    } else {           // V^T[bh][n][s]: tile rows are n, cols advance along s
        gsrc = (const char*)Vt + ((size_t)(bh * 64 + srow) * S_ + half * 1024) * 2 + scolS;
        cstride = (size_t)8 * S_ * 2;
        tstep = 128;
    }
    char* dst = &Sbuf[half][0] + role * 8192 + lane * 16;
    const char* Kh = &Sbuf[half][0];
    const char* Vh = Kh + 8192;

    bf16x8 sreg[8];
#pragma unroll
    for (int j = 0; j < 8; ++j) sreg[j] = *(const bf16x8*)(gsrc + j * cstride);

    f32x16 oo[2] = {};
    float lrun = 0.f;

#pragma unroll 1
    for (int kt = 0; kt < 16; ++kt) {
        __syncthreads();   // prior readers done, LDS free
#pragma unroll
        for (int j = 0; j < 8; ++j) *(bf16x8*)(dst + j * 1024) = sreg[j];
        __syncthreads();   // tile visible to all 4 waves
        if (kt < 15) {     // T14: issue next tile's loads; land during compute
            const char* p = gsrc + (size_t)(kt + 1) * tstep;
#pragma unroll
            for (int j = 0; j < 8; ++j) sreg[j] = *(const bf16x8*)(p + j * cstride);
        }

        const bool mk = (mflags >> (4 * kt)) & 0xFULL;
        float lsum = 0.f;
#pragma unroll
        for (int kb2 = 0; kb2 < 2; ++kb2) {
            const int row = kb2 * 32 + lo;
            const int rsw = (row & 7) << 4;
            f32x16 sa = {};
            __builtin_amdgcn_s_setprio(1);
#pragma unroll
            for (int kb = 0; kb < 4; ++kb) {
                bf16x8 aK = *(const bf16x8*)(Kh + row * 128 + ((kb * 32 + hi * 16) ^ rsw));
                sa = __builtin_amdgcn_mfma_f32_32x32x16_bf16(aK, bQ[kb], sa, 0, 0, 0);
            }
            __builtin_amdgcn_s_setprio(0);
            float pp[16];
            if (!mk) {
#pragma unroll
                for (int r = 0; r < 16; ++r) pp[r] = __builtin_amdgcn_exp2f(sa[r]);
            } else {
#pragma unroll
                for (int r = 0; r < 16; ++r) {
                    int kv = half * 1024 + kt * 64 + kb2 * 32 + (r & 3) + 8 * (r >> 2) + 4 * hi;
                    float madd = masks[b * S_ + kv] ? 0.f : NEGL2;
                    pp[r] = __builtin_amdgcn_exp2f(sa[r] + madd);
                }
            }
            float s8[8];
#pragma unroll
            for (int i = 0; i < 8; ++i) s8[i] = pp[i] + pp[i + 8];
            lsum += ((s8[0] + s8[1]) + (s8[2] + s8[3])) + ((s8[4] + s8[5]) + (s8[6] + s8[7]));

#pragma unroll
            for (int ks2 = 0; ks2 < 2; ++ks2) {
                const float* q8 = pp + ks2 * 8;
                unsigned u0 = pk2(q8[0], q8[1]);
                unsigned u1 = pk2(q8[2], q8[3]);
                unsigned u2 = pk2(q8[4], q8[5]);
                unsigned u3 = pk2(q8[6], q8[7]);
                asm("v_permlane32_swap_b32 %0, %1" : "+v"(u0), "+v"(u2));
                asm("v_permlane32_swap_b32 %0, %1" : "+v"(u1), "+v"(u3));
                union { unsigned u[4]; bf16x8 v; } pa;
                pa.u[0] = u0; pa.u[1] = u1; pa.u[2] = u2; pa.u[3] = u3;
                const int ks = kb2 * 2 + ks2;
                __builtin_amdgcn_s_setprio(1);
#pragma unroll
                for (int nb = 0; nb < 2; ++nb) {
                    const int vr = nb * 32 + lo;
                    bf16x8 aV = *(const bf16x8*)(Vh + vr * 128 +
                                                 ((ks * 32 + hi * 16) ^ ((vr & 7) << 4)));
                    oo[nb] = __builtin_amdgcn_mfma_f32_32x32x16_bf16(aV, pa.v, oo[nb], 0, 0, 0);
                }
                __builtin_amdgcn_s_setprio(0);
            }
        }
        lrun += lsum + __shfl_xor(lsum, 32, 64);
    }

    // ---- merge: waves 2,3 (half 1) hand partials to waves 0,1 (half 0) ----
    __syncthreads();
    float* mbuf = (float*)&Sbuf[0][0];   // 16KB = 2 q-subs x 2048 floats
    if (w >= 2) {
        float* d = mbuf + qs * 2048;
#pragma unroll
        for (int nb = 0; nb < 2; ++nb)
#pragma unroll
            for (int r = 0; r < 16; ++r)
                d[(nb * 16 + r) * 64 + lane] = oo[nb][r];
        Lr[qs][lane] = lrun;
    }
    __syncthreads();
    if (w < 2) {
        const float* s = mbuf + qs * 2048;
#pragma unroll
        for (int nb = 0; nb < 2; ++nb)
#pragma unroll
            for (int r = 0; r < 16; ++r)
                oo[nb][r] += s[(nb * 16 + r) * 64 + lane];
        float inv = 1.f / (lrun + Lr[qs][lane]);

        // transpose O^T -> O via LDS scratch (disjoint from mbuf), coalesced store
        char* ot = (char*)&Sbuf[1][0] + qs * 8192;   // [32 q][72 n] bf16
#pragma unroll
        for (int nb = 0; nb < 2; ++nb)
#pragma unroll
            for (int tq = 0; tq < 4; ++tq) {
                int n0 = tq * 8 + hi * 4 + nb * 32;
                *(unsigned*)(ot + lo * 144 + n0 * 2) =
                    pk2(oo[nb][tq * 4 + 0] * inv, oo[nb][tq * 4 + 1] * inv);
                *(unsigned*)(ot + lo * 144 + n0 * 2 + 4) =
                    pk2(oo[nb][tq * 4 + 2] * inv, oo[nb][tq * 4 + 3] * inv);
            }
#pragma unroll
        for (int pass = 0; pass < 4; ++pass) {
            int chunk = hi + pass * 2;
            bf16x8 vv = *(const bf16x8*)(ot + lo * 144 + chunk * 16);
            *(bf16x8*)(Oa + (size_t)(b * S_ + qt * 64 + qs * 32 + lo) * D_ + h * 64 + chunk * 8) = vv;
        }
    }
}

extern "C" void kernel_launch(void* const* d_in, const int* in_sizes, int n_in,
                              void* d_out, int out_size, void* d_ws, size_t ws_size,
                              hipStream_t stream) {
    (void)in_sizes; (void)n_in; (void)out_size; (void)ws_size;
    const float* x  = (const float*)d_in[0];
    const int* masks = (const int*)d_in[1];
    const float* Wq = (const float*)d_in[2];
    const float* bq = (const float*)d_in[3];
    const float* Wk = (const float*)d_in[4];
    const float* bk = (const float*)d_in[5];
    const float* Wv = (const float*)d_in[6];
    const float* bv = (const float*)d_in[7];
    const float* Wo = (const float*)d_in[8];
    const float* bo = (const float*)d_in[9];
    float* out = (float*)d_out;

    char* ws = (char*)d_ws;
    size_t off = 0;
    auto alloc = [&](size_t bytes) {
        void* p = ws + off;
        off += (bytes + 255) & ~(size_t)255;
        return p;
    };
    bf16* Xb  = (bf16*)alloc((size_t)BS_ * D_ * 2);
    // NOTE: Wqt..Wot must stay contiguous (prep / gemm_qkv rely on it)
    bf16* Wqt = (bf16*)alloc((size_t)D_ * D_ * 2);
    bf16* Wkt = (bf16*)alloc((size_t)D_ * D_ * 2);
    bf16* Wvt = (bf16*)alloc((size_t)D_ * D_ * 2);
    bf16* Wot = (bf16*)alloc((size_t)D_ * D_ * 2);
    bf16* Qb  = (bf16*)alloc((size_t)BS_ * D_ * 2);
    bf16* Kb2 = (bf16*)alloc((size_t)BS_ * D_ * 2);
    bf16* Vtb = (bf16*)alloc((size_t)BS_ * D_ * 2);
    bf16* Ab  = (bf16*)alloc((size_t)BS_ * D_ * 2);
    (void)Wkt; (void)Wvt;

    prep<<<dim3(1536 + 576), 256, 0, stream>>>(x, Wq, Wk, Wv, Wo, Xb, Wqt);

    gemm_qkv<<<dim3(64, 18), 256, 0, stream>>>(Xb, Wqt, bq, bk, bv, Qb, Kb2, Vtb);

    attn_fwd10<<<dim3(32, 24), 256, 0, stream>>>(Qb, Kb2, Vtb, masks, Ab);

    gemm_out<<<dim3(128, 6), 256, 0, stream>>>(Ab, Wot, bo, out);
}